// Round 8
// baseline (373.853 us; speedup 1.0000x reference)
//
#include <hip/hip_runtime.h>
#include <hip/hip_bf16.h>
#include <math.h>

#define B 64
#define N 512
#define C 1024
#define K_NEIGH 32
// Band half-width: need DELTA - bisect_window/2 - E' > E'. With the fused
// kernel the threshold decisions run on fp32 MFMA accumulators, so
// E' = E_gemm ~ 0.15 only (9-sigma fp16-input GEMM error; no fp16-store term).
// wide window = 2800/2^12 = 0.68 -> DELTA > 0.34 + 0.30 = 0.64; DELTA = 0.9.
// fast-bracket window = 20/2^5 = 0.625 -> equally safe.
// Non-band elements are strictly separated from the true rank-32 cut;
// band candidates are exactly rechecked in fp32 (bitwise-matching dots).
#define DELTA 0.9f
#define BISECT_ITERS 12

typedef __attribute__((ext_vector_type(8))) _Float16 half8;
typedef __attribute__((ext_vector_type(4))) float f32x4;

__device__ __forceinline__ half8 cvt8(float4 a, float4 b) {
    half8 g;
    g[0] = (_Float16)a.x; g[1] = (_Float16)a.y; g[2] = (_Float16)a.z; g[3] = (_Float16)a.w;
    g[4] = (_Float16)b.x; g[5] = (_Float16)b.y; g[6] = (_Float16)b.z; g[7] = (_Float16)b.w;
    return g;
}

// ---------------------------------------------------------------------------
// Fused kernel: per block, compute S[row0..row0+127][0..511] = fp16(x)*fp16(x)^T
// for one batch strip (full rows!), stage the fp32 result as fp16 in LDS,
// then run the per-row rank-32 threshold logic in-kernel. S never touches HBM.
//
// Geometry: 256 blocks (64 batches x 4 strips) = 1/CU. 512 thr = 8 waves in
// 2x4, wave tile 64x128 (acc[4][8] f32x4). BK=32, rotated 2-phase pipeline
// with raw barrier (r6-proven: vmcnt NOT drained across it).
// B staging covers the WHOLE batch (512 rows x 32 k per step, 64KB -- same
// bytes/step as r6's A+B); A-fragments read from the B buffer at row0+ offset
// (A rows are a subset of B rows) -> no A staging, no diag special-case.
// LDS: union{ staging 2x32KB ; S-tile 128x512 fp16 = 128KB } = 128KB.
// Frag layout (proven r0..r6): granule (s,row) = 8 fp16 of k=s*8.. at
// s*512+row; A-frag A[m=lane&15][k=quad*8+j]; C/D col=lane&15, row=quad*4+e.
//
// Epilogue thresh (per wave, 16 rows serial, all logic wave-local):
//  * sigma bracket: P_est = 1.542*sigma; 5-iter bisection on +-10 if the
//    bracket VALIDATES by count, else wide 12-iter fallback (exactness safe).
//  * band [P-DELTA, P+DELTA] rechecked with wave-cooperative exact fp32 dots
//    (same fma/reduce order as all prior rounds -> identical values);
//    exact tie-corrected threshold; emit 512-bit mask + deg^-0.5.
// ---------------------------------------------------------------------------
__global__ __launch_bounds__(512, 2) void gemm_thresh(const float* __restrict__ x,
                                                      unsigned long long* __restrict__ masks,
                                                      float* __restrict__ dinv) {
    __shared__ union {
        half8    Bst[2][2048];     // staging: 2 x 32KB (4 granule-cols x 512 rows)
        _Float16 S[128][512];      // epilogue S-tile: 128KB
    } sh;

    // XCD-aware swizzle: XCD = id%8 owns batches xcd*8..+7; a batch's 4
    // strips are consecutive slots -> co-resident on one XCD, share x[b] L2.
    const int id    = blockIdx.x;          // 0..255
    const int xcd   = id & 7;
    const int slot  = id >> 3;             // 0..31
    const int b     = xcd * 8 + (slot >> 2);
    const int strip = slot & 3;
    const int row0  = strip * 128;
    const float* xb = x + (size_t)b * N * C;

    const int t    = threadIdx.x;
    const int w    = t >> 6;
    const int lane = t & 63;
    const int quad = lane >> 4;
    const int lid  = lane & 15;
    const int wr   = (w >> 2) * 64;        // 2 wave-rows of 64
    const int wc   = (w & 3) * 128;        // 4 wave-cols of 128

    f32x4 acc[4][8];
#pragma unroll
    for (int r = 0; r < 4; r++)
#pragma unroll
        for (int c = 0; c < 8; c++)
#pragma unroll
            for (int e = 0; e < 4; e++) acc[r][c][e] = 0.f;

    // B staging: thread t owns batch-row t, 32 k-floats (= 8 float4 = 4 granules)
    const float* prow = xb + (size_t)t * C;

    float4 rx[8];
#pragma unroll
    for (int i = 0; i < 8; i++) rx[i] = ((const float4*)prow)[i];

    const int NIT = C / 32;                // 32 K-steps
    for (int it = 0; it < NIT; ++it) {
        const int p = it & 1;
        // cvt + ds_write step it (vmcnt waits on loads with a full iter of cover)
#pragma unroll
        for (int s = 0; s < 4; s++)
            sh.Bst[p][s * 512 + t] = cvt8(rx[2 * s], rx[2 * s + 1]);
        // issue loads for step it+1 (stay in flight across the barrier)
        if (it + 1 < NIT) {
            const float4* pp = (const float4*)(prow + (it + 1) * 32);
#pragma unroll
            for (int i = 0; i < 8; i++) rx[i] = pp[i];
        }
        asm volatile("s_waitcnt lgkmcnt(0)" ::: "memory");
        __builtin_amdgcn_s_barrier();
        // compute step it from buf p; A-frags come from the B buffer (row0+)
        const half8* Bb = &sh.Bst[p][0];
        half8 va[4];
#pragma unroll
        for (int r = 0; r < 4; r++) va[r] = Bb[quad * 512 + row0 + wr + r * 16 + lid];
        __builtin_amdgcn_s_setprio(1);
#pragma unroll
        for (int c = 0; c < 8; c++) {
            half8 vb = Bb[quad * 512 + wc + c * 16 + lid];
#pragma unroll
            for (int r = 0; r < 4; r++)
                acc[r][c] = __builtin_amdgcn_mfma_f32_16x16x32_f16(va[r], vb, acc[r][c], 0, 0, 0);
        }
        __builtin_amdgcn_s_setprio(0);
    }

    // ---- epilogue: stage S-tile to LDS (fp16; decisions still budgeted) ----
    __syncthreads();   // all waves done reading Bst before overwrite
#pragma unroll
    for (int r = 0; r < 4; r++)
#pragma unroll
        for (int c = 0; c < 8; c++)
#pragma unroll
            for (int e = 0; e < 4; e++)
                sh.S[wr + r * 16 + quad * 4 + e][wc + c * 16 + lid] = (_Float16)acc[r][c][e];
    __syncthreads();

    // ---- thresh phase: wave w handles rows w*16 .. w*16+15 ----
    for (int rr = 0; rr < 16; ++rr) {
        const int lr   = w * 16 + rr;          // local row in strip
        const int gi   = row0 + lr;            // batch-row index (= diag col)
        const int grow = b * N + gi;           // global row

        float v0[8];
#pragma unroll
        for (int k = 0; k < 8; k++) v0[k] = (float)sh.S[lr][lane + 64 * k];

        const float* xi = x + ((size_t)b * N + gi) * C;
        float4 ai[4];
#pragma unroll
        for (int q = 0; q < 4; q++) ai[q] = *(const float4*)(xi + q * 256 + lane * 4);

        // sigma-based bracket estimate (diagonal excluded)
        float sum2 = 0.f;
#pragma unroll
        for (int k = 0; k < 8; k++) {
            const float v = ((lane + 64 * k) == gi) ? 0.f : v0[k];
            sum2 = fmaf(v, v, sum2);
        }
#pragma unroll
        for (int off = 32; off > 0; off >>= 1) sum2 += __shfl_xor(sum2, off);
        const float Pest = 1.542f * sqrtf(sum2 * (1.0f / 511.0f));
        const float bhi = Pest + 10.f, blo = Pest - 10.f;
        int chk_hi = 0, chk_lo = 0;
#pragma unroll
        for (int k = 0; k < 8; k++) {
            chk_hi += __popcll(__ballot(v0[k] > bhi));
            chk_lo += __popcll(__ballot(v0[k] > blo));
        }

        // bisection: invariant cnt(lo) >= 32, cnt(hi) <= 31, cnt(p)=#{v>p}
        float lo, hi;
        int nit;
        if (chk_hi <= K_NEIGH - 1 && chk_lo >= K_NEIGH) {
            lo = blo; hi = bhi; nit = 5;                    // window 0.625
        } else {
            lo = -1400.f; hi = 1400.f; nit = BISECT_ITERS;  // window 0.684
        }
        for (int i2 = 0; i2 < nit; i2++) {
            const float mid = 0.5f * (lo + hi);
            int cc = 0;
#pragma unroll
            for (int k = 0; k < 8; k++) cc += __popcll(__ballot(v0[k] > mid));
            if (cc >= K_NEIGH) lo = mid; else hi = mid;
        }
        const float P   = 0.5f * (lo + hi);
        const float hiB = P + DELTA, loB = P - DELTA;

        int cA = 0;
#pragma unroll
        for (int k = 0; k < 8; k++) cA += __popcll(__ballot(v0[k] > hiB));
        const int m_need = K_NEIGH - cA;   // >= 1

        // band candidates: one per lane
        int cnt = 0, myj = -1;
#pragma unroll
        for (int kq = 0; kq < 8; kq++) {
            unsigned long long bm = __ballot(v0[kq] >= loB && v0[kq] <= hiB);
            while (bm) {
                int bl = __ffsll(bm) - 1;
                bm &= bm - 1;
                if (cnt == lane) myj = bl + 64 * kq;
                cnt++;
            }
        }
        const int nc = cnt < 64 ? cnt : 64;

        // wave-cooperative exact fp32 dots (order identical to prior rounds)
        float ex = -INFINITY;
        for (int c2 = 0; c2 < nc; c2++) {
            const int j = __shfl(myj, c2);
            const float* xj = x + ((size_t)b * N + j) * C;
            float s = 0.f;
#pragma unroll
            for (int q = 0; q < 4; q++) {
                float4 bv = *(const float4*)(xj + q * 256 + lane * 4);
                s = fmaf(ai[q].x, bv.x, s);
                s = fmaf(ai[q].y, bv.y, s);
                s = fmaf(ai[q].z, bv.z, s);
                s = fmaf(ai[q].w, bv.w, s);
            }
#pragma unroll
            for (int off = 32; off > 0; off >>= 1) s += __shfl_xor(s, off);
            if (lane == c2) ex = s;
        }

        // exact threshold T = m_need-th largest band value (tie-correct)
        float val = ex, T = -INFINITY;
        for (int i2 = 0; i2 < m_need; i2++) {
            float M = val;
#pragma unroll
            for (int off = 32; off > 0; off >>= 1) M = fmaxf(M, __shfl_xor(M, off));
            T = M;
            unsigned long long ball = __ballot(val == M);
            int first = __ffsll(ball) - 1;
            if (lane == first) val = -INFINITY;
        }
        const int dec = (lane < nc && ex >= T) ? 1 : 0;

        // adjacency bits: certain-above -> 1, band -> exact decision, else 0
        int bits[8];
#pragma unroll
        for (int kq = 0; kq < 8; kq++) bits[kq] = (v0[kq] > hiB) ? 1 : 0;
        for (int c2 = 0; c2 < nc; c2++) {
            int j = __shfl(myj, c2);
            int d = __shfl(dec, c2);
            if ((j & 63) == lane) bits[j >> 6] = d;
        }

        unsigned long long msk[8];
        int deg = 0;
#pragma unroll
        for (int kq = 0; kq < 8; kq++) {
            msk[kq] = __ballot(bits[kq] != 0);
            deg += __popcll(msk[kq]);
        }
        if (lane == 0) {
#pragma unroll
            for (int kq = 0; kq < 8; kq++) masks[(size_t)grow * 8 + kq] = msk[kq];
            dinv[grow] = rsqrtf((float)deg);
        }
    }
}

// ---------------------------------------------------------------------------
// Kernel 2: out[b,i,j] = maskbit ? dinv[b,i]*dinv[b,j] : 0
// ---------------------------------------------------------------------------
__global__ __launch_bounds__(256) void scale_adj(float* __restrict__ Sout,
                                                 const unsigned long long* __restrict__ masks,
                                                 const float* __restrict__ dinv) {
    const int idx = blockIdx.x * 256 + threadIdx.x;   // float4 index
    const int jq = idx & 127;
    const int i  = (idx >> 7) & (N - 1);
    const int b  = idx >> 16;
    const int row = (b << 9) | i;
    const int j0 = jq * 4;

    const unsigned long long mk = masks[(size_t)row * 8 + (j0 >> 6)];
    const float di = dinv[row];
    float4 dj = ((const float4*)dinv)[(b << 7) | jq];

    float4 o;
    o.x = ((mk >> ((j0 + 0) & 63)) & 1ull) ? di * dj.x : 0.f;
    o.y = ((mk >> ((j0 + 1) & 63)) & 1ull) ? di * dj.y : 0.f;
    o.z = ((mk >> ((j0 + 2) & 63)) & 1ull) ? di * dj.z : 0.f;
    o.w = ((mk >> ((j0 + 3) & 63)) & 1ull) ? di * dj.w : 0.f;
    ((float4*)Sout)[idx] = o;
}

// ---------------------------------------------------------------------------
extern "C" void kernel_launch(void* const* d_in, const int* in_sizes, int n_in,
                              void* d_out, int out_size, void* d_ws, size_t ws_size,
                              hipStream_t stream) {
    const float* x = (const float*)d_in[0];
    float* out = (float*)d_out;                                // final fp32 output
    unsigned long long* masks = (unsigned long long*)d_ws;     // B*N*8 u64 = 2MB
    float* dinv = (float*)(masks + (size_t)B * N * 8);         // B*N floats

    gemm_thresh<<<dim3(B * 4), 512, 0, stream>>>(x, masks, dinv);  // 256 blocks = 1/CU
    const int total4 = B * N * N / 4;
    scale_adj<<<total4 / 256, 256, 0, stream>>>(out, masks, dinv);
}

// Round 9
// 278.745 us; speedup vs baseline: 1.3412x; 1.3412x over previous
//
#include <hip/hip_runtime.h>
#include <hip/hip_bf16.h>
#include <math.h>

#define B 64
#define N 512
#define C 1024
#define K_NEIGH 32
// Band half-width: need DELTA - bisect_window/2 - E' > E', where
// E' = E_gemm + E_store. E_gemm ~ 0.15 (9-sigma fp16-hi GEMM error);
// E_store <= 0.07 (fp16 storage rounding for band-relevant |v| <= 256).
// max window = 2800/2^12 = 0.68 -> DELTA > 0.34 + 0.44 = 0.78; DELTA = 0.9.
// (tight-bracket path: window 20/2^5 = 0.625 -> even stricter separation)
// Non-band elements are strictly separated from the true rank-32 cut;
// band candidates are exactly rechecked in fp32 (bitwise-matching dots).
#define DELTA 0.9f
#define BISECT_ITERS 12

typedef __attribute__((ext_vector_type(8))) _Float16 half8;
typedef __attribute__((ext_vector_type(4))) float f32x4;

__device__ __forceinline__ half8 cvt8(float4 a, float4 b) {
    half8 g;
    g[0] = (_Float16)a.x; g[1] = (_Float16)a.y; g[2] = (_Float16)a.z; g[3] = (_Float16)a.w;
    g[4] = (_Float16)b.x; g[5] = (_Float16)b.y; g[6] = (_Float16)b.z; g[7] = (_Float16)b.w;
    return g;
}

// ---------------------------------------------------------------------------
// Kernel 1: S16[b] = fp16( fp16(x[b]) * fp16(x[b])^T ) via f16 MFMA.
// 256x256 tile, 512 thr = 8 waves (2x4, wave tile 128x64), rotated 2-phase
// pipeline with raw barrier (r6-proven: vmcnt NOT drained across barriers).
// Round-9 change: BK 32 -> 64. We are pinned at 1 block/CU (grid 256), so
// the barrier count is the pure lever: 32 -> 16 barrier drains per block,
// 64 MFMA/wave between barriers (was 32). LDS 2x(2x32KB) = 128KB (fits 160).
// K-accumulation order unchanged (kk=0,1 within tile = same ascending k
// steps of 32) -> S16 bit-identical to r6/r7.
// LDS granule layout (proven): granule (s,row) = 8 fp16 of k=s*8.. at index
// s*256+row; frag read = 16 consecutive granules = 256B, conflict-free.
// A-frag: A[m=lane&15][k=quad*8+j] (+kk*32); C/D: col=lane&15, row=quad*4+e.
// Spill tripwire: WRITE_SIZE >> 35MB means the 16-float4 prefetch spilled.
// ---------------------------------------------------------------------------
__global__ __launch_bounds__(512, 2) void gemm_f16(const float* __restrict__ x,
                                                   _Float16* __restrict__ S16) {
    __shared__ half8 Ah[2][2048];   // 2 x 32KB (8 granule-cols x 256 rows)
    __shared__ half8 Bh[2][2048];   // 2 x 32KB

    // XCD-aware swizzle: XCD = id%8 owns batches xcd*8..+7 (4 tiles each
    // consecutive) -> tiles of one batch co-resident, share x[b] in L2.
    const int id   = blockIdx.x;           // 0..255
    const int xcd  = id & 7;
    const int slot = id >> 3;              // 0..31
    const int b    = xcd * 8 + (slot >> 2);
    const int tile = slot & 3;
    const int ti = tile >> 1, tj = tile & 1;
    const int row0 = ti * 256;
    const int col0 = tj * 256;
    const float* xb = x + (size_t)b * N * C;
    const bool diag = (ti == tj);

    const int t    = threadIdx.x;
    const int w    = t >> 6;
    const int lane = t & 63;
    const int quad = lane >> 4;
    const int lid  = lane & 15;
    const int wr   = (w >> 2) * 128;       // 2 wave-rows of 128
    const int wc   = (w & 3) * 64;         // 4 wave-cols of 64

    // staging: thread t -> row (t>>1), k-half (t&1)*32 floats (granules g0..g0+3)
    const int srow = t >> 1;
    const int g0   = (t & 1) * 4;
    const int koff = (t & 1) * 32;

    f32x4 acc[8][4];
#pragma unroll
    for (int r = 0; r < 8; r++)
#pragma unroll
        for (int c = 0; c < 4; c++)
#pragma unroll
            for (int e = 0; e < 4; e++) acc[r][c][e] = 0.f;

    const float* pArow = xb + (size_t)(row0 + srow) * C + koff;
    const float* pBrow = xb + (size_t)(col0 + srow) * C + koff;

    float4 ra[8], rb[8];
    // ---- prologue: issue loads for K-tile 0 ----
    {
        const float4* pa = (const float4*)pArow;
#pragma unroll
        for (int i = 0; i < 8; i++) ra[i] = pa[i];
        if (!diag) {
            const float4* pb = (const float4*)pBrow;
#pragma unroll
            for (int i = 0; i < 8; i++) rb[i] = pb[i];
        }
    }

    const int NT = C / 64;                  // 16 K-tiles
    for (int tt = 0; tt < NT; ++tt) {
        const int p = tt & 1;
        // ---- cvt + ds_write K-tile tt (vmcnt waits on loads from iter tt-1,
        //      which had a full iteration of cover) ----
#pragma unroll
        for (int i = 0; i < 4; i++)
            Ah[p][(g0 + i) * 256 + srow] = cvt8(ra[2 * i], ra[2 * i + 1]);
        if (!diag) {
#pragma unroll
            for (int i = 0; i < 4; i++)
                Bh[p][(g0 + i) * 256 + srow] = cvt8(rb[2 * i], rb[2 * i + 1]);
        }
        // ---- issue loads for K-tile tt+1 (stay in flight across barrier) ----
        if (tt + 1 < NT) {
            const float4* pa = (const float4*)(pArow + (tt + 1) * 64);
#pragma unroll
            for (int i = 0; i < 8; i++) ra[i] = pa[i];
            if (!diag) {
                const float4* pb = (const float4*)(pBrow + (tt + 1) * 64);
#pragma unroll
                for (int i = 0; i < 8; i++) rb[i] = pb[i];
            }
        }
        // ---- barrier draining LDS only; global prefetch NOT drained ----
        asm volatile("s_waitcnt lgkmcnt(0)" ::: "memory");
        __builtin_amdgcn_s_barrier();
        // ---- compute K-tile tt from buf p: 2 sub-steps of k=32 ----
        const half8* Ab = &Ah[p][0];
        const half8* Bb = diag ? Ab : &Bh[p][0];
#pragma unroll
        for (int kk = 0; kk < 2; kk++) {
            const int s = (kk * 4 + quad) * 256;
            half8 vb[4];
#pragma unroll
            for (int c = 0; c < 4; c++) vb[c] = Bb[s + wc + c * 16 + lid];
            __builtin_amdgcn_s_setprio(1);
#pragma unroll
            for (int r = 0; r < 8; r++) {
                half8 va = Ab[s + wr + r * 16 + lid];
#pragma unroll
                for (int c = 0; c < 4; c++)
                    acc[r][c] = __builtin_amdgcn_mfma_f32_16x16x32_f16(va, vb[c], acc[r][c], 0, 0, 0);
            }
            __builtin_amdgcn_s_setprio(0);
        }
    }

    _Float16* Sb = S16 + (size_t)b * N * N;
#pragma unroll
    for (int r = 0; r < 8; r++) {
#pragma unroll
        for (int c = 0; c < 4; c++) {
#pragma unroll
            for (int e = 0; e < 4; e++) {
                const int grow = row0 + wr + r * 16 + quad * 4 + e;
                const int gcol = col0 + wc + c * 16 + lid;
                Sb[(size_t)grow * N + gcol] = (_Float16)acc[r][c][e];
            }
        }
    }
}

// ---------------------------------------------------------------------------
// Kernel 2: per row -- pivot P via ballot-popcount bisection; band [P-d,P+d]
// rechecked with wave-cooperative exact fp32 dots; exact threshold among
// band; emit 512-bit adjacency mask + deg^-0.5. One wave/row, 4 rows/block.
// (r7 version: sigma bracket + 2-candidate ILP dots + hoisted xi loads.)
// ---------------------------------------------------------------------------
__global__ __launch_bounds__(256) void thresh_mask(const _Float16* __restrict__ S16,
                                                   const float* __restrict__ x,
                                                   unsigned long long* __restrict__ masks,
                                                   float* __restrict__ dinv) {
    // XCD-aware swizzle: XCD = id%8 owns batches xcd*8..+7, so each XCD's
    // band dots re-read its own 2MB x[b] slice from its private L2.
    const int id   = blockIdx.x;               // 0..8191
    const int xcd  = id & 7;
    const int slot = id >> 3;                  // 0..1023
    const int bsw  = xcd * 8 + (slot >> 7);    // batch
    const int rblk = slot & 127;               // 4-row block within batch
    const int row  = bsw * N + rblk * 4 + (threadIdx.x >> 6);
    const int lane = threadIdx.x & 63;
    const _Float16* Srow = S16 + (size_t)row * N;

    const int bb_ = row >> 9, ii = row & (N - 1);
    const float* xi = x + ((size_t)bb_ * N + ii) * C;

    float v0[8];
#pragma unroll
    for (int k = 0; k < 8; k++) v0[k] = (float)Srow[lane + 64 * k];   // col = lane + 64k

    // hoisted xi fragments (latency hides under the ballot work below)
    float4 ai[4];
#pragma unroll
    for (int q = 0; q < 4; q++) ai[q] = *(const float4*)(xi + q * 256 + lane * 4);

    // --- sigma-based bracket estimate (diagonal excluded) ---
    float sum2 = 0.f;
#pragma unroll
    for (int k = 0; k < 8; k++) {
        const float v = ((lane + 64 * k) == ii) ? 0.f : v0[k];
        sum2 = fmaf(v, v, sum2);
    }
#pragma unroll
    for (int off = 32; off > 0; off >>= 1) sum2 += __shfl_xor(sum2, off);
    const float Pest = 1.542f * sqrtf(sum2 * (1.0f / 511.0f));
    const float bhi = Pest + 10.f, blo = Pest - 10.f;
    int chk_hi = 0, chk_lo = 0;
#pragma unroll
    for (int k = 0; k < 8; k++) {
        chk_hi += __popcll(__ballot(v0[k] > bhi));
        chk_lo += __popcll(__ballot(v0[k] > blo));
    }

    // --- bisection: invariant cnt(lo) >= 32, cnt(hi) <= 31, cnt(p)=#{v>p} ---
    float lo, hi;
    int nit;
    if (chk_hi <= K_NEIGH - 1 && chk_lo >= K_NEIGH) {
        lo = blo; hi = bhi; nit = 5;               // window 20/32 = 0.625
    } else {
        lo = -1400.f; hi = 1400.f; nit = BISECT_ITERS;   // window 0.684
    }
    for (int it = 0; it < nit; it++) {
        const float mid = 0.5f * (lo + hi);
        int c = 0;
#pragma unroll
        for (int k = 0; k < 8; k++) c += __popcll(__ballot(v0[k] > mid));
        if (c >= K_NEIGH) lo = mid; else hi = mid;
    }
    const float P   = 0.5f * (lo + hi);
    const float hiB = P + DELTA, loB = P - DELTA;

    // certainly-in count (<= 31 by construction: hiB > hi)
    int cA = 0;
#pragma unroll
    for (int k = 0; k < 8; k++) cA += __popcll(__ballot(v0[k] > hiB));
    const int m_need = K_NEIGH - cA;   // >= 1 (loB < lo)

    // band candidates: one per lane
    int cnt = 0, myj = -1;
#pragma unroll
    for (int kq = 0; kq < 8; kq++) {
        unsigned long long bm = __ballot(v0[kq] >= loB && v0[kq] <= hiB);
        while (bm) {
            int bl = __ffsll(bm) - 1;
            bm &= bm - 1;
            if (cnt == lane) myj = bl + 64 * kq;
            cnt++;
        }
    }
    const int nc = cnt < 64 ? cnt : 64;

    // wave-cooperative exact dots, 2 candidates per pass (ILP); per-candidate
    // fma/reduce order identical to the serial version -> same fp32 values.
    float ex = -INFINITY;
    for (int c2 = 0; c2 < nc; c2 += 2) {
        const int c3 = (c2 + 1 < nc) ? c2 + 1 : c2;
        const int j0 = __shfl(myj, c2);
        const int j1 = __shfl(myj, c3);
        const float* xj0 = x + ((size_t)bb_ * N + j0) * C;
        const float* xj1 = x + ((size_t)bb_ * N + j1) * C;
        float s0 = 0.f, s1 = 0.f;
#pragma unroll
        for (int q = 0; q < 4; q++) {
            float4 b0 = *(const float4*)(xj0 + q * 256 + lane * 4);
            float4 b1 = *(const float4*)(xj1 + q * 256 + lane * 4);
            s0 = fmaf(ai[q].x, b0.x, s0);
            s0 = fmaf(ai[q].y, b0.y, s0);
            s0 = fmaf(ai[q].z, b0.z, s0);
            s0 = fmaf(ai[q].w, b0.w, s0);
            s1 = fmaf(ai[q].x, b1.x, s1);
            s1 = fmaf(ai[q].y, b1.y, s1);
            s1 = fmaf(ai[q].z, b1.z, s1);
            s1 = fmaf(ai[q].w, b1.w, s1);
        }
#pragma unroll
        for (int off = 32; off > 0; off >>= 1) {
            s0 += __shfl_xor(s0, off);
            s1 += __shfl_xor(s1, off);
        }
        if (lane == c2) ex = s0;
        if (lane == c3 && c3 != c2) ex = s1;
    }

    // exact threshold T = m_need-th largest band value (tie-correct)
    float val = ex, T = -INFINITY;
    for (int it = 0; it < m_need; it++) {
        float M = val;
#pragma unroll
        for (int off = 32; off > 0; off >>= 1) M = fmaxf(M, __shfl_xor(M, off));
        T = M;
        unsigned long long ball = __ballot(val == M);
        int first = __ffsll(ball) - 1;
        if (lane == first) val = -INFINITY;
    }
    const int dec = (lane < nc && ex >= T) ? 1 : 0;

    // adjacency bits: certain-above -> 1, band -> exact decision, else 0
    int bits[8];
#pragma unroll
    for (int kq = 0; kq < 8; kq++) bits[kq] = (v0[kq] > hiB) ? 1 : 0;
    for (int c2 = 0; c2 < nc; c2++) {
        int j = __shfl(myj, c2);
        int d = __shfl(dec, c2);
        if ((j & 63) == lane) bits[j >> 6] = d;
    }

    unsigned long long msk[8];
    int deg = 0;
#pragma unroll
    for (int kq = 0; kq < 8; kq++) {
        msk[kq] = __ballot(bits[kq] != 0);
        deg += __popcll(msk[kq]);
    }
    if (lane == 0) {
#pragma unroll
        for (int kq = 0; kq < 8; kq++) masks[(size_t)row * 8 + kq] = msk[kq];
        dinv[row] = rsqrtf((float)deg);
    }
}

// ---------------------------------------------------------------------------
// Kernel 3: out[b,i,j] = maskbit ? dinv[b,i]*dinv[b,j] : 0
// ---------------------------------------------------------------------------
__global__ __launch_bounds__(256) void scale_adj(float* __restrict__ Sout,
                                                 const unsigned long long* __restrict__ masks,
                                                 const float* __restrict__ dinv) {
    const int idx = blockIdx.x * 256 + threadIdx.x;   // float4 index
    const int jq = idx & 127;
    const int i  = (idx >> 7) & (N - 1);
    const int b  = idx >> 16;
    const int row = (b << 9) | i;
    const int j0 = jq * 4;

    const unsigned long long mk = masks[(size_t)row * 8 + (j0 >> 6)];
    const float di = dinv[row];
    float4 dj = ((const float4*)dinv)[(b << 7) | jq];

    float4 o;
    o.x = ((mk >> ((j0 + 0) & 63)) & 1ull) ? di * dj.x : 0.f;
    o.y = ((mk >> ((j0 + 1) & 63)) & 1ull) ? di * dj.y : 0.f;
    o.z = ((mk >> ((j0 + 2) & 63)) & 1ull) ? di * dj.z : 0.f;
    o.w = ((mk >> ((j0 + 3) & 63)) & 1ull) ? di * dj.w : 0.f;
    ((float4*)Sout)[idx] = o;
}

// ---------------------------------------------------------------------------
extern "C" void kernel_launch(void* const* d_in, const int* in_sizes, int n_in,
                              void* d_out, int out_size, void* d_ws, size_t ws_size,
                              hipStream_t stream) {
    const float* x = (const float*)d_in[0];
    float* out = (float*)d_out;                      // final fp32 output
    _Float16* S16 = (_Float16*)d_out;                // staged fp16 S' (first 33.5MB)
    unsigned long long* masks = (unsigned long long*)d_ws;     // B*N*8 u64 = 2MB
    float* dinv = (float*)(masks + (size_t)B * N * 8);         // B*N floats

    gemm_f16<<<dim3(B * 4), 512, 0, stream>>>(x, S16);         // 256 blocks = 1/CU
    thresh_mask<<<B * N / 4, 256, 0, stream>>>(S16, x, masks, dinv);
    const int total4 = B * N * N / 4;
    scale_adj<<<total4 / 256, 256, 0, stream>>>(out, masks, dinv);
}